// Round 6
// baseline (155.476 us; speedup 1.0000x reference)
//
#include <hip/hip_runtime.h>
#include <math.h>

#define Bsz 2048
#define Ddim 32
#define Nsz 8192
#define Kk 30
#define TPB 256
#define ROWS 4                    // rows (i) per block
#define JSL 2                     // j-dimension slices
#define JTILE (Bsz / JSL)         // 1024 j's per block
#define JCH (JTILE / TPB)         // 4 chunks per thread
#define NBLK ((Bsz / ROWS) * JSL) // 1024 blocks
#define NW (Nsz / 32)             // 256 bitset words per row

// R3 shape (best: 84.5us) + occupancy fix. zi is block-uniform; reading it
// from LDS is a same-address broadcast (~free). R4 failed because the
// compiler HOISTED the loop-invariant LDS reads into 128 VGPRs and spilled.
// Fix: opaque zero offset re-clobbered by empty asm each chunk iteration ->
// reads cannot be CSE'd across chunks -> zi never held live in registers.
// VGPR ~130-160 -> launch_bounds(256,3): 3 blocks/CU (12 waves/CU, +50% TLP
// vs R3) with ~40 regs of anti-spill headroom.
__global__ __launch_bounds__(TPB, 3) void softnp_main(
    const float* __restrict__ z,
    const int*   __restrict__ pre_knn,
    const int*   __restrict__ samp,
    float*       __restrict__ wsden,   // [JSL][Bsz] partial denominators
    float*       __restrict__ wsnum)   // [JSL][Bsz] partial masked numerators
{
    __shared__ unsigned bits4[NW][ROWS];   // 4 KB, word-interleaved by row
    __shared__ int      sampsh[JTILE];     // 4 KB
    __shared__ float    zish[ROWS * Ddim]; // 512 B
    __shared__ int      rowsi[ROWS];
    __shared__ float    rden[4][ROWS], rnum[4][ROWS];

    const int t  = threadIdx.x;
    const int rg = blockIdx.x >> 1;
    const int sl = blockIdx.x & 1;
    const int i0 = rg * ROWS;
    const int jb = sl * JTILE;

    // ---- stage: zero bitsets, slice of samp -> LDS, z_i -> LDS ----
    #pragma unroll
    for (int c = 0; c < (NW * ROWS) / TPB; ++c)
        ((unsigned*)bits4)[t + c * TPB] = 0u;
    #pragma unroll
    for (int c = 0; c < JCH; ++c)
        sampsh[t + c * TPB] = samp[jb + t + c * TPB];
    if (t < ROWS * Ddim) zish[t] = z[(size_t)i0 * Ddim + t];
    if (t < ROWS) rowsi[t] = samp[i0 + t];
    __syncthreads();

    // ---- fill bitsets: 4 rows x 30 entries ----
    if (t < ROWS * 32) {
        const int r = t >> 5, k = t & 31;
        if (k < Kk) {
            const int id = pre_knn[(size_t)rowsi[r] * Kk + k];
            atomicOr(&bits4[id >> 5][r], 1u << (id & 31));
        }
    }
    __syncthreads();

    // ---- |z_i|^2 per row (one-time LDS broadcast reads) ----
    const float4* z4 = (const float4*)zish;
    float si2[ROWS];
    #pragma unroll
    for (int r = 0; r < ROWS; ++r) {
        float s = 0.f;
        #pragma unroll
        for (int d = 0; d < Ddim / 4; ++d) {
            const float4 a = z4[r * (Ddim / 4) + d];
            s += a.x * a.x + a.y * a.y + a.z * a.z + a.w * a.w;
        }
        si2[r] = s;
    }

    float den[ROWS] = {0.f, 0.f, 0.f, 0.f};
    float num[ROWS] = {0.f, 0.f, 0.f, 0.f};

    // ---- single-pass j loop, double-buffered global loads ----
    const float4* zg = (const float4*)z;
    int j = jb + t;
    float4 cur[8];
    #pragma unroll
    for (int d = 0; d < 8; ++d) cur[d] = zg[(size_t)j * 8 + d];

    int zoff = 0;   // always 0, but opaque to the compiler inside the loop
    #pragma unroll
    for (int c = 0; c < JCH; ++c) {
        float4 nxt[8];
        if (c + 1 < JCH) {
            #pragma unroll
            for (int d = 0; d < 8; ++d) nxt[d] = zg[(size_t)(j + TPB) * 8 + d];
        }

        // Re-clobber zoff: LDS zi reads below cannot be hoisted/CSE'd across
        // chunk iterations (the R4 spill trap), yet cost ~nothing per read
        // (wave-uniform address -> LDS broadcast).
        asm volatile("" : "+v"(zoff));
        const float4* zzi = z4 + zoff;

        float dot[ROWS] = {0.f, 0.f, 0.f, 0.f};
        float sj2 = 0.f;
        #pragma unroll
        for (int d = 0; d < 8; ++d) {
            const float4 v = cur[d];
            sj2 += v.x * v.x + v.y * v.y + v.z * v.z + v.w * v.w;
            #pragma unroll
            for (int r = 0; r < ROWS; ++r) {
                const float4 a = zzi[r * 8 + d];   // broadcast ds_read_b128
                dot[r] += a.x * v.x + a.y * v.y + a.z * v.z + a.w * v.w;
            }
        }

        const int   sj = sampsh[t + c * TPB];
        const uint4 bw = ((const uint4*)bits4)[sj >> 5]; // 4 rows, 1 ds_read_b128
        const unsigned bsel[4] = {bw.x, bw.y, bw.z, bw.w};
        #pragma unroll
        for (int r = 0; r < ROWS; ++r) {
            const float d2 = fmaxf(si2[r] + sj2 - 2.f * dot[r], 0.f);
            const bool diag = (j == i0 + r);
            const float e = diag ? 0.f : __expf(-sqrtf(d2));
            den[r] += e;
            if (!diag && ((bsel[r] >> (sj & 31)) & 1u)) num[r] += e;
        }

        if (c + 1 < JCH) {
            #pragma unroll
            for (int d = 0; d < 8; ++d) cur[d] = nxt[d];
        }
        j += TPB;
    }

    // ---- wave shuffle reduction (no barriers), 4-wave LDS combine ----
    const int lane = t & 63, wv = t >> 6;
    #pragma unroll
    for (int r = 0; r < ROWS; ++r) {
        #pragma unroll
        for (int off = 32; off > 0; off >>= 1) {
            den[r] += __shfl_xor(den[r], off, 64);
            num[r] += __shfl_xor(num[r], off, 64);
        }
    }
    if (lane == 0) {
        #pragma unroll
        for (int r = 0; r < ROWS; ++r) { rden[wv][r] = den[r]; rnum[wv][r] = num[r]; }
    }
    __syncthreads();

    if (t < ROWS) {
        float D = 0.f, Nm = 0.f;
        #pragma unroll
        for (int w = 0; w < 4; ++w) { D += rden[w][t]; Nm += rnum[w][t]; }
        wsden[sl * Bsz + i0 + t] = D;   // pure overwrite: no zero-init needed
        wsnum[sl * Bsz + i0 + t] = Nm;
    }
}

__global__ __launch_bounds__(TPB) void softnp_final(
    const float* __restrict__ wsden,
    const float* __restrict__ wsnum,
    float*       __restrict__ out)
{
    __shared__ float rl[4], rc[4];
    const int t = threadIdx.x;
    float loss = 0.f, vcnt = 0.f;
    #pragma unroll
    for (int c = 0; c < Bsz / TPB; ++c) {
        const int r = t + c * TPB;
        const float D  = wsden[r] + wsden[Bsz + r];
        const float Nm = wsnum[r] + wsnum[Bsz + r];
        if (Nm > 0.f) {             // valid <=> any masked neighbor (no underflow)
            loss -= __logf(Nm / D + 1e-8f);
            vcnt += 1.f;
        }
    }
    #pragma unroll
    for (int off = 32; off > 0; off >>= 1) {
        loss += __shfl_xor(loss, off, 64);
        vcnt += __shfl_xor(vcnt, off, 64);
    }
    const int lane = t & 63, wv = t >> 6;
    if (lane == 0) { rl[wv] = loss; rc[wv] = vcnt; }
    __syncthreads();
    if (t == 0) {
        const float L = rl[0] + rl[1] + rl[2] + rl[3];
        const float C = rc[0] + rc[1] + rc[2] + rc[3];
        out[0] = (C > 0.f) ? L / C : 0.f;
    }
}

extern "C" void kernel_launch(void* const* d_in, const int* in_sizes, int n_in,
                              void* d_out, int out_size, void* d_ws, size_t ws_size,
                              hipStream_t stream)
{
    const float* z       = (const float*)d_in[0];
    const int*   pre_knn = (const int*)d_in[1];
    const int*   samp    = (const int*)d_in[2];
    float*       out     = (float*)d_out;
    float*       wsden   = (float*)d_ws;             // [JSL][Bsz]
    float*       wsnum   = wsden + JSL * Bsz;        // [JSL][Bsz]

    softnp_main<<<dim3(NBLK), dim3(TPB), 0, stream>>>(z, pre_knn, samp, wsden, wsnum);
    softnp_final<<<dim3(1), dim3(TPB), 0, stream>>>(wsden, wsnum, out);
}

// Round 7
// 92.240 us; speedup vs baseline: 1.6856x; 1.6856x over previous
//
#include <hip/hip_runtime.h>
#include <math.h>

#define Bsz 2048
#define Ddim 32
#define Nsz 8192
#define Kk 30

// ---------------- Kernel A: mask matrix + |z_j|^2 table ----------------
// M[j][wc] bit r = ( samp[j] in knn-set(32*wc + r) ), exact bitset semantics
// (duplicate knn ids dedupe like the reference's .any()). Diagonal handled in
// the den kernel. Grid: 64 wordcols x 4 j-slices, TPB=256, 32KB LDS bitsets.
__global__ __launch_bounds__(256) void softnp_mask(
    const float* __restrict__ z,
    const int*   __restrict__ pre_knn,
    const int*   __restrict__ samp,
    unsigned*    __restrict__ M,     // [Bsz][64]
    float*       __restrict__ sq)    // [Bsz]
{
    __shared__ unsigned bits[32 * (Nsz / 32)];   // 32 rows x 256 words = 32 KB
    const int t  = threadIdx.x;
    const int wc = blockIdx.x >> 2;          // word column: rows 32wc..32wc+31
    const int js = (blockIdx.x & 3) * 512;   // j slice

    // zero bitsets (8192 words) via uint4
    uint4* b4 = (uint4*)bits;
    #pragma unroll
    for (int c = 0; c < 8; ++c) b4[t + c * 256] = make_uint4(0u, 0u, 0u, 0u);
    __syncthreads();

    // fill: 32 rows x 30 knn entries = 960 gathers
    for (int v = t; v < 32 * Kk; v += 256) {
        const int r  = v / Kk, k = v - r * Kk;
        const int id = pre_knn[(size_t)samp[wc * 32 + r] * Kk + k];
        atomicOr(&bits[r * (Nsz / 32) + (id >> 5)], 1u << (id & 31));
    }
    __syncthreads();

    // test phase: 512 j's, 2 per thread
    #pragma unroll
    for (int c = 0; c < 2; ++c) {
        const int j  = js + t + c * 256;
        const int sj = samp[j];
        const int w  = sj >> 5, bsh = sj & 31;
        unsigned word = 0u;
        #pragma unroll
        for (int r = 0; r < 32; ++r)
            word |= ((bits[r * (Nsz / 32) + w] >> bsh) & 1u) << r;
        M[(size_t)j * 64 + wc] = word;
        if (wc == 0) {                       // |z_j|^2 table, written once
            float s = 0.f;
            const float4* zj = (const float4*)(z + (size_t)j * Ddim);
            #pragma unroll
            for (int d = 0; d < 8; ++d) {
                const float4 a = zj[d];
                s += a.x * a.x + a.y * a.y + a.z * a.z + a.w * a.w;
            }
            sq[j] = s;
        }
    }
}

// ---------------- Kernel B: den/num, lane-owns-row ----------------
// Lane owns row i: zi = 32 VGPR. j is WAVE-UNIFORM -> z_j reads scalarize
// (SMEM), |z_j|^2 from table, mask from precomputed M. No LDS, no per-lane
// VMEM in the hot loop, ~70 VGPR -> 4+ waves/SIMD. Grid 8 i-tiles x 128
// j-slices of 16.
__global__ __launch_bounds__(256) void softnp_den(
    const float* __restrict__ z,
    const unsigned* __restrict__ M,
    const float* __restrict__ sq,
    float*       __restrict__ wsden,   // [128][Bsz]
    float*       __restrict__ wsnum)   // [128][Bsz]
{
    const int t  = threadIdx.x;
    const int it = blockIdx.x >> 7;
    const int s  = blockIdx.x & 127;
    const int i0 = it * 256;
    const int j0 = s * 16;
    const int row = i0 + t;

    // own row into registers + |z_i|^2
    float4 zi[8];
    const float4* zr = (const float4*)(z + (size_t)row * Ddim);
    #pragma unroll
    for (int d = 0; d < 8; ++d) zi[d] = zr[d];
    float si2 = 0.f;
    #pragma unroll
    for (int d = 0; d < 8; ++d)
        si2 += zi[d].x * zi[d].x + zi[d].y * zi[d].y
             + zi[d].z * zi[d].z + zi[d].w * zi[d].w;

    // mask words for my row, all 16 jj's (contiguous-ish 32B/wave loads)
    unsigned mw[16];
    #pragma unroll
    for (int c = 0; c < 16; ++c)
        mw[c] = M[(size_t)(j0 + c) * 64 + ((unsigned)row >> 5)];
    const int bsh = row & 31;

    float den = 0.f, num = 0.f;
    #pragma unroll
    for (int c = 0; c < 16; ++c) {
        const int jg = j0 + c;                       // wave-uniform
        const float* zj = z + (size_t)jg * Ddim;     // -> s_load path
        float dot = 0.f;
        #pragma unroll
        for (int d = 0; d < Ddim; ++d) dot += zj[d] * (((const float*)zi)[d]);
        const float d2 = fmaxf(si2 + sq[jg] - 2.f * dot, 0.f);
        const float e  = (jg == row) ? 0.f : __expf(-sqrtf(d2));
        den += e;
        num += ((mw[c] >> bsh) & 1u) ? e : 0.f;
    }

    wsden[(size_t)s * Bsz + row] = den;   // unique (s,row): overwrite-only
    wsnum[(size_t)s * Bsz + row] = num;
}

// ---------------- final1: per-row loss, 8 block partials ----------------
__global__ __launch_bounds__(256) void softnp_final1(
    const float* __restrict__ wsden,
    const float* __restrict__ wsnum,
    float*       __restrict__ wsf)     // [16]: loss[8], cnt[8]
{
    __shared__ float rl[4], rc[4];
    const int t = threadIdx.x;
    const int r = blockIdx.x * 256 + t;
    float D = 0.f, Nm = 0.f;
    #pragma unroll 8
    for (int s = 0; s < 128; ++s) {
        D  += wsden[(size_t)s * Bsz + r];
        Nm += wsnum[(size_t)s * Bsz + r];
    }
    float loss = 0.f, cnt = 0.f;
    if (Nm > 0.f) {               // valid <=> any masked neighbor
        loss = -__logf(Nm / D + 1e-8f);
        cnt  = 1.f;
    }
    #pragma unroll
    for (int off = 32; off > 0; off >>= 1) {
        loss += __shfl_xor(loss, off, 64);
        cnt  += __shfl_xor(cnt,  off, 64);
    }
    const int lane = t & 63, wv = t >> 6;
    if (lane == 0) { rl[wv] = loss; rc[wv] = cnt; }
    __syncthreads();
    if (t == 0) {
        wsf[blockIdx.x]     = rl[0] + rl[1] + rl[2] + rl[3];
        wsf[8 + blockIdx.x] = rc[0] + rc[1] + rc[2] + rc[3];
    }
}

__global__ void softnp_final2(const float* __restrict__ wsf,
                              float* __restrict__ out)
{
    const int t = threadIdx.x;           // 64 threads
    float l = (t < 8) ? wsf[t]     : 0.f;
    float c = (t < 8) ? wsf[8 + t] : 0.f;
    #pragma unroll
    for (int off = 4; off > 0; off >>= 1) {
        l += __shfl_xor(l, off, 64);
        c += __shfl_xor(c, off, 64);
    }
    if (t == 0) out[0] = (c > 0.f) ? l / c : 0.f;
}

extern "C" void kernel_launch(void* const* d_in, const int* in_sizes, int n_in,
                              void* d_out, int out_size, void* d_ws, size_t ws_size,
                              hipStream_t stream)
{
    const float* z       = (const float*)d_in[0];
    const int*   pre_knn = (const int*)d_in[1];
    const int*   samp    = (const int*)d_in[2];
    float*       out     = (float*)d_out;

    // ws carve (all regions fully overwritten every launch -> no init):
    unsigned* M     = (unsigned*)d_ws;                    // 2048*64 u32 = 512 KB
    float*    sq    = (float*)(M + (size_t)Bsz * 64);     // 8 KB
    float*    wsden = sq + Bsz;                           // 128*2048 = 1 MB
    float*    wsnum = wsden + (size_t)128 * Bsz;          // 1 MB
    float*    wsf   = wsnum + (size_t)128 * Bsz;          // 64 B

    softnp_mask  <<<dim3(256),  dim3(256), 0, stream>>>(z, pre_knn, samp, M, sq);
    softnp_den   <<<dim3(1024), dim3(256), 0, stream>>>(z, M, sq, wsden, wsnum);
    softnp_final1<<<dim3(8),    dim3(256), 0, stream>>>(wsden, wsnum, wsf);
    softnp_final2<<<dim3(1),    dim3(64),  0, stream>>>(wsf, out);
}